// Round 1
// baseline (1654.191 us; speedup 1.0000x reference)
//
#include <hip/hip_runtime.h>
#include <hip/hip_cooperative_groups.h>
#include <math.h>

namespace cg = cooperative_groups;

#define NN   96
#define EE   1024
#define HID  256
#define IND  64
#define ZD   64
#define UU   4560
#define NL   4656
#define NBLK 96
#define NTHR 384
#define TOT  (NBLK*NTHR)
#define ITERS 50

struct Params {
  const float* x; const int* ei; const float* adj;
  const float* W1; const float* b1; const float* g1; const float* be1;
  const float* W2; const float* b2; const float* g2; const float* be2;
  const float* Wmu; const float* bmu; const float* Wlv; const float* blv;
  const float* Wd1; const float* bd1; const float* Wd2; const float* bd2;
  const float* eps; float* out;
};

// workspace as device globals (written before read on every launch)
__device__ float d_Anorm[NN*NN];
__device__ float d_M1[NN*HID];   // XW, then HW2
__device__ float d_M2[NN*HID];   // H1pre, then H2pre
__device__ float d_h1[NN*HID];
__device__ float d_dinv[NN];
__device__ float d_mean[HID];
__device__ float d_istd[HID];
__device__ float d_gvec[HID];
__device__ float d_z[ZD];
__device__ float d_d1[HID];
__device__ float d_vec[NL];
__device__ float d_X[2][NN*NN];
__device__ float d_ssq[ITERS+1];

__device__ __forceinline__ float wsum(float v) {
  v += __shfl_xor(v, 32, 64);
  v += __shfl_xor(v, 16, 64);
  v += __shfl_xor(v,  8, 64);
  v += __shfl_xor(v,  4, 64);
  v += __shfl_xor(v,  2, 64);
  v += __shfl_xor(v,  1, 64);
  return v;
}

__device__ __forceinline__ int tri_idx(int a, int c) {
  // a < c, index into triu_indices(N,1) row-major order
  return a*95 - (a*(a-1))/2 + (c - a - 1);
}

__global__ void __launch_bounds__(NTHR) gvae_kernel(Params p) {
  cg::grid_group grid = cg::this_grid();
  const int b    = blockIdx.x;
  const int t    = threadIdx.x;
  const int g    = b*NTHR + t;
  const int lane = t & 63;
  const int gw   = g >> 6;          // global wave id (NTHR % 64 == 0)

  __shared__ float Xls[NN*NN];      // 36 KB
  __shared__ float Arow[NN];
  __shared__ float ndrow[NN];
  __shared__ float rowsq[NN];
  __shared__ int   nbrL[NN];
  __shared__ float sdegA;
  __shared__ int   s_cnt;

  //---------------- P0: A row b + dinv; XW = x@W1; X0 + ssq init ----------------
  if (t < NN) Arow[t] = 0.0f;
  __syncthreads();
  for (int e = t; e < EE; e += NTHR) {
    int src = p.ei[e];
    int dst = p.ei[EE + e];
    if (src == b) Arow[dst] = 1.0f;   // benign same-value races
  }
  if (t == 0) Arow[b] = 1.0f;         // max(A, I)
  __syncthreads();
  if (t == 0) {
    float s = 0.0f;
    for (int j = 0; j < NN; ++j) s += Arow[j];
    d_dinv[b] = 1.0f / sqrtf(s);
  }
  if (t < NN) d_Anorm[b*NN + t] = Arow[t];
  if (g < NN*HID) {
    int i = g >> 8, c = g & 255;
    float acc = 0.0f;
    for (int d = 0; d < IND; ++d) acc += p.x[i*IND + d] * p.W1[d*HID + c];
    d_M1[g] = acc;
  }
  if (g < NN*NN) d_X[0][g] = 1.0f/96.0f;
  if (g < ITERS+1) d_ssq[g] = (g == 0) ? 1.0f : 0.0f;
  grid.sync();

  //---------------- P1: A_norm = A * dinv_i * dinv_j (in place) ----------------
  if (g < NN*NN) {
    int i = g / NN, j = g - i*NN;
    d_Anorm[g] = d_Anorm[g] * d_dinv[i] * d_dinv[j];
  }
  grid.sync();

  //---------------- P2: H1pre = A_norm @ XW + b1 ----------------
  if (g < NN*HID) {
    int i = g >> 8, c = g & 255;
    float acc = p.b1[c];
    for (int j = 0; j < NN; ++j) acc += d_Anorm[i*NN + j] * d_M1[j*HID + c];
    d_M2[g] = acc;
  }
  grid.sync();

  //---------------- P3: BN1 stats (wave per column) ----------------
  if (gw < HID) {
    int c = gw;
    float v0 = d_M2[lane*HID + c];
    float v1 = (lane < 32) ? d_M2[(64+lane)*HID + c] : 0.0f;
    float mean = wsum(v0 + v1) / 96.0f;
    float a0 = v0 - mean;
    float a1 = (lane < 32) ? (v1 - mean) : 0.0f;
    float var = wsum(a0*a0 + a1*a1) / 96.0f;
    if (lane == 0) { d_mean[c] = mean; d_istd[c] = 1.0f / sqrtf(var + 1e-5f); }
  }
  grid.sync();

  //---------------- P4: h1 = relu(bn) ----------------
  if (g < NN*HID) {
    int c = g & 255;
    float v = (d_M2[g] - d_mean[c]) * d_istd[c] * p.g1[c] + p.be1[c];
    d_h1[g] = fmaxf(v, 0.0f);
  }
  grid.sync();

  //---------------- P5: HW2 = h1 @ W2 ----------------
  if (g < NN*HID) {
    int i = g >> 8, c = g & 255;
    float acc = 0.0f;
    for (int k = 0; k < HID; ++k) acc += d_h1[i*HID + k] * p.W2[k*HID + c];
    d_M1[g] = acc;
  }
  grid.sync();

  //---------------- P6: H2pre = A_norm @ HW2 + b2 ----------------
  if (g < NN*HID) {
    int i = g >> 8, c = g & 255;
    float acc = p.b2[c];
    for (int j = 0; j < NN; ++j) acc += d_Anorm[i*NN + j] * d_M1[j*HID + c];
    d_M2[g] = acc;
  }
  grid.sync();

  //---------------- P7: BN2 stats ----------------
  if (gw < HID) {
    int c = gw;
    float v0 = d_M2[lane*HID + c];
    float v1 = (lane < 32) ? d_M2[(64+lane)*HID + c] : 0.0f;
    float mean = wsum(v0 + v1) / 96.0f;
    float a0 = v0 - mean;
    float a1 = (lane < 32) ? (v1 - mean) : 0.0f;
    float var = wsum(a0*a0 + a1*a1) / 96.0f;
    if (lane == 0) { d_mean[c] = mean; d_istd[c] = 1.0f / sqrtf(var + 1e-5f); }
  }
  grid.sync();

  //---------------- P8: h2 in-register, g_vec = colsum(h2)/N ----------------
  if (gw < HID) {
    int c = gw;
    float mean = d_mean[c], istd = d_istd[c];
    float ga = p.g2[c], be = p.be2[c];
    float v0 = d_M2[lane*HID + c];
    float h0 = fmaxf((v0 - mean)*istd*ga + be, 0.0f);
    float h1v = 0.0f;
    if (lane < 32) {
      float v1 = d_M2[(64+lane)*HID + c];
      h1v = fmaxf((v1 - mean)*istd*ga + be, 0.0f);
    }
    float s = wsum(h0 + h1v);
    if (lane == 0) d_gvec[c] = s / 96.0f;
  }
  grid.sync();

  //---------------- P9: mu, lv, z ----------------
  if (g < ZD) {
    float am = p.bmu[g], al = p.blv[g];
    for (int c = 0; c < HID; ++c) {
      float gv = d_gvec[c];
      am += gv * p.Wmu[c*ZD + g];
      al += gv * p.Wlv[c*ZD + g];
    }
    al = fminf(fmaxf(al, -4.0f), 4.0f);
    d_z[g] = am + p.eps[g] * expf(0.5f * al);
  }
  grid.sync();

  //---------------- P10: d1 = relu(z @ Wd1 + bd1) ----------------
  if (g < HID) {
    float acc = p.bd1[g];
    for (int d = 0; d < ZD; ++d) acc += d_z[d] * p.Wd1[d*HID + g];
    d_d1[g] = fmaxf(acc, 0.0f);
  }
  grid.sync();

  //---------------- P11: vec = tanh(d1 @ Wd2 + bd2) ----------------
  if (g < NL) {
    float acc = p.bd2[g];
    for (int c = 0; c < HID; ++c) acc += d_d1[c] * p.Wd2[c*NL + g];
    d_vec[g] = tanhf(acc);
  }
  grid.sync();

  //---------------- MPM prologue (block b == row i) ----------------
  const int kk = t >> 2;   // 0..95
  const int qq = t & 3;    // 0..3
  float breg[24];

  // wave 0: degA(row b) + neighbor list via ballot compaction (ascending j)
  if (t < 64) {
    float s = p.adj[b*NN + t] + ((t < 32) ? p.adj[b*NN + 64 + t] : 0.0f);
    s = wsum(s);
    if (t == 0) sdegA = s + 1.0f;   // diag of Agt is 1
    int j = t;
    bool is1 = (j != b) && (p.adj[b*NN + j] > 0.5f);
    unsigned long long m1 = __ballot(is1);
    if (is1) nbrL[__popcll(m1 & ((1ull << t) - 1))] = j;
    int c1 = __popcll(m1);
    bool is2 = (t < 32) && ((64 + t) != b) && (p.adj[b*NN + 64 + t] > 0.5f);
    unsigned long long m2 = __ballot(is2);
    if (is2) nbrL[c1 + __popcll(m2 & ((1ull << t) - 1))] = 64 + t;
    if (t == 0) s_cnt = c1 + __popcll(m2);
  }

  // breg = B[kk][qq*24 .. +24) with diag zeroed (implements l != k); degB on the fly
  {
    float bs = 0.0f;
    const int lb = qq*24;
    #pragma unroll
    for (int s = 0; s < 24; ++s) {
      int l = lb + s;
      float v = 0.0f;
      if (l != kk) {
        int a  = kk < l ? kk : l;
        int cc = kk < l ? l : kk;
        v = 1.0f / (1.0f + expf(-d_vec[tri_idx(a, cc)]));
      }
      breg[s] = v;
      bs += v;
    }
    float tot = bs + __shfl_xor(bs, 1, 64);
    tot += __shfl_xor(tot, 2, 64);
    __syncthreads();   // sdegA visible
    if (qq == 0) ndrow[kk] = 1.0f / (fabsf(sdegA - (tot + 1.0f)) + 1.0f);
  }
  __syncthreads();

  //---------------- MPM: 50 iterations, 1 grid.sync each ----------------
  int cur = 0;
  for (int it = 0; it < ITERS; ++it) {
    // exact power-of-2 rescale in place of per-iter normalization (homogeneous step)
    float s2 = d_ssq[it];
    int ex;
    (void)frexpf(sqrtf(s2), &ex);
    float scale = ldexpf(1.0f, -ex);
    for (int idx = t; idx < NN*NN; idx += NTHR) Xls[idx] = d_X[cur][idx] * scale;
    __syncthreads();

    float acc = 0.0f;
    const int cnt = s_cnt;
    for (int n = 0; n < cnt; ++n) {
      const int j = nbrL[n];
      const float4* xp = reinterpret_cast<const float4*>(&Xls[j*NN + qq*24]);
      float vm = 0.0f;
      #pragma unroll
      for (int s6 = 0; s6 < 6; ++s6) {
        float4 xv = xp[s6];
        vm = fmaxf(vm, breg[4*s6+0] * xv.x);
        vm = fmaxf(vm, breg[4*s6+1] * xv.y);
        vm = fmaxf(vm, breg[4*s6+2] * xv.z);
        vm = fmaxf(vm, breg[4*s6+3] * xv.w);
      }
      vm = fmaxf(vm, __shfl_xor(vm, 1, 64));
      vm = fmaxf(vm, __shfl_xor(vm, 2, 64));
      acc += vm;      // ascending-j order matches reference sum order
    }
    if (qq == 0) {
      float xn = Xls[b*NN + kk] * ndrow[kk] + acc;
      d_X[cur ^ 1][b*NN + kk] = xn;
      rowsq[kk] = xn * xn;
    }
    __syncthreads();
    if (t == 0) {
      float rs = 0.0f;
      for (int k2 = 0; k2 < NN; ++k2) rs += rowsq[k2];
      atomicAdd(&d_ssq[it+1], rs);
    }
    __threadfence();
    grid.sync();
    cur ^= 1;
  }

  //---------------- final true normalization ----------------
  if (g < NN*NN) {
    float inv = 1.0f / sqrtf(d_ssq[ITERS]);
    p.out[g] = d_X[cur][g] * inv;
  }
}

extern "C" void kernel_launch(void* const* d_in, const int* in_sizes, int n_in,
                              void* d_out, int out_size, void* d_ws, size_t ws_size,
                              hipStream_t stream) {
  Params prm;
  prm.x   = (const float*)d_in[0];
  prm.ei  = (const int*  )d_in[1];
  prm.adj = (const float*)d_in[2];
  prm.W1  = (const float*)d_in[3];
  prm.b1  = (const float*)d_in[4];
  prm.g1  = (const float*)d_in[5];
  prm.be1 = (const float*)d_in[6];
  prm.W2  = (const float*)d_in[7];
  prm.b2  = (const float*)d_in[8];
  prm.g2  = (const float*)d_in[9];
  prm.be2 = (const float*)d_in[10];
  prm.Wmu = (const float*)d_in[11];
  prm.bmu = (const float*)d_in[12];
  prm.Wlv = (const float*)d_in[13];
  prm.blv = (const float*)d_in[14];
  prm.Wd1 = (const float*)d_in[15];
  prm.bd1 = (const float*)d_in[16];
  prm.Wd2 = (const float*)d_in[17];
  prm.bd2 = (const float*)d_in[18];
  prm.eps = (const float*)d_in[19];
  prm.out = (float*)d_out;

  void* args[] = { &prm };
  hipLaunchCooperativeKernel(reinterpret_cast<void*>(&gvae_kernel),
                             dim3(NBLK), dim3(NTHR), args, 0, stream);
}

// Round 2
// 840.402 us; speedup vs baseline: 1.9683x; 1.9683x over previous
//
#include <hip/hip_runtime.h>
#include <math.h>

#define NN    96
#define ANLD  97            // padded leading dim for A in LDS (bank-conflict-free row sums)
#define EE    1024
#define HID   256
#define IND   64
#define ZD    64
#define NL    4656
#define NBLK  96
#define NTHR  384
#define ITERS 50
#define NBARS 56

struct Params {
  const float* x; const int* ei; const float* adj;
  const float* W1; const float* b1; const float* g1; const float* be1;
  const float* W2; const float* b2; const float* g2; const float* be2;
  const float* Wmu; const float* bmu; const float* Wlv; const float* blv;
  const float* Wd1; const float* bd1; const float* Wd2; const float* bd2;
  const float* eps; float* out;
};

// persistent device globals (all rewritten each launch before use)
__device__ float  d_XW[NN*HID];
__device__ float  d_H1pre[NN*HID];
__device__ float  d_h1[NN*HID];
__device__ float  d_HW2[NN*HID];
__device__ float  d_H2pre[NN*HID];
__device__ float  d_vec[NL];
__device__ float4 d_X[2][NN*NN/4];
__device__ float  d_ssq[ITERS+1];
// barrier state: monotonic counters + launch epoch (zero-initialized at module load;
// invariant: each launch adds exactly NBLK to every counter and 1 to epoch)
__device__ int    d_bar[NBARS];
__device__ int    d_epoch;

__device__ __forceinline__ float wsum(float v) {
  v += __shfl_xor(v, 32, 64);
  v += __shfl_xor(v, 16, 64);
  v += __shfl_xor(v,  8, 64);
  v += __shfl_xor(v,  4, 64);
  v += __shfl_xor(v,  2, 64);
  v += __shfl_xor(v,  1, 64);
  return v;
}

__device__ __forceinline__ int tri_idx(int a, int c) {
  return a*95 - (a*(a-1))/2 + (c - a - 1);
}

// Lightweight grid barrier. Entry: all waves drain their outstanding stores
// (s_waitcnt is per-wave; without this, t0's release would not cover other
// waves' in-flight global stores), block-sync, then t0 does a device-scope
// release-RMW arrive and spins on the counter (agent atomics bypass stale
// caches), then an acquire fence (L1/L2 inv) before releasing the block.
__device__ __forceinline__ void gbar(int idx, int target) {
  asm volatile("s_waitcnt vmcnt(0) lgkmcnt(0)" ::: "memory");
  __syncthreads();
  if (threadIdx.x == 0) {
    __hip_atomic_fetch_add(&d_bar[idx], 1, __ATOMIC_RELEASE, __HIP_MEMORY_SCOPE_AGENT);
    while (__hip_atomic_load(&d_bar[idx], __ATOMIC_RELAXED, __HIP_MEMORY_SCOPE_AGENT) < target)
      __builtin_amdgcn_s_sleep(1);
    __threadfence();   // acquire: invalidate L1 + XCD L2 so the block reads fresh data
  }
  __syncthreads();
}

__global__ void __launch_bounds__(NTHR) gvae_kernel(Params p) {
  const int b    = blockIdx.x;
  const int t    = threadIdx.x;
  const int g    = b*NTHR + t;

  __shared__ float  An[NN*ANLD];       // full normalized adjacency, per block (redundant)
  __shared__ float4 Xls4[NN*NN/4];
  float* Xls = (float*)Xls4;
  __shared__ float  sm[HID], si[HID], sg[HID], sd1[HID];
  __shared__ float  sz[ZD];
  __shared__ float  sdv[NN], ndrow[NN], rowsq[NN];
  __shared__ int    nbrL[NN];
  __shared__ float  sdegA;
  __shared__ int    s_cnt;

  // epoch read happens-before any barrier arrival of this launch (incrementer
  // only runs after ALL blocks passed the final barrier of the SAME launch)
  const int target = (__hip_atomic_load(&d_epoch, __ATOMIC_RELAXED, __HIP_MEMORY_SCOPE_AGENT) + 1) * NBLK;

  //---------------- Phase A: redundant A/Anorm in LDS; XW distributed; inits ----------------
  for (int i = t; i < NN*ANLD; i += NTHR) An[i] = 0.0f;
  __syncthreads();
  for (int e = t; e < EE; e += NTHR) {
    int s = p.ei[e], d = p.ei[EE + e];
    An[s*ANLD + d] = 1.0f;              // benign same-value LDS races
  }
  if (t < NN) An[t*ANLD + t] = 1.0f;    // max(A, I)
  __syncthreads();
  if (t < NN) {
    float s = 0.0f;
    for (int j = 0; j < NN; ++j) s += An[t*ANLD + j];
    sdv[t] = 1.0f / sqrtf(s);
  }
  __syncthreads();
  for (int idx = t; idx < NN*NN; idx += NTHR) {
    int i = idx / NN, j = idx - i*NN;
    An[i*ANLD + j] *= sdv[i] * sdv[j];
  }
  if (g < NN*HID) {                     // XW = x @ W1 (distributed)
    int i = g >> 8, c = g & 255;
    float acc = 0.0f;
    for (int d = 0; d < IND; ++d) acc += p.x[i*IND + d] * p.W1[d*HID + c];
    d_XW[g] = acc;
  }
  if (g < NN*NN/4) d_X[0][g] = make_float4(1.0f/96, 1.0f/96, 1.0f/96, 1.0f/96);
  if (g < ITERS+1) d_ssq[g] = (g == 0) ? 1.0f : 0.0f;
  gbar(0, target);

  //---------------- Phase B: H1pre = Anorm @ XW + b1 (distributed; Anorm local) ----------------
  if (g < NN*HID) {
    int i = g >> 8, c = g & 255;
    float acc = p.b1[c];
    for (int j = 0; j < NN; ++j) acc += An[i*ANLD + j] * d_XW[j*HID + c];
    d_H1pre[g] = acc;
  }
  gbar(1, target);

  //---------------- Phase C: BN1 stats (redundant per block) + h1 ----------------
  if (t < HID) {
    float s = 0.0f;
    for (int i = 0; i < NN; ++i) s += d_H1pre[i*HID + t];
    float mean = s / 96.0f;
    float vs = 0.0f;
    for (int i = 0; i < NN; ++i) { float a = d_H1pre[i*HID + t] - mean; vs += a*a; }
    sm[t] = mean;
    si[t] = 1.0f / sqrtf(vs/96.0f + 1e-5f);
  }
  __syncthreads();
  if (g < NN*HID) {
    int c = g & 255;
    d_h1[g] = fmaxf((d_H1pre[g] - sm[c]) * si[c] * p.g1[c] + p.be1[c], 0.0f);
  }
  gbar(2, target);

  //---------------- Phase D: HW2 = h1 @ W2 (distributed) ----------------
  if (g < NN*HID) {
    int i = g >> 8, c = g & 255;
    float acc = 0.0f;
    for (int k = 0; k < HID; ++k) acc += d_h1[i*HID + k] * p.W2[k*HID + c];
    d_HW2[g] = acc;
  }
  gbar(3, target);

  //---------------- Phase E: H2pre = Anorm @ HW2 + b2 ----------------
  if (g < NN*HID) {
    int i = g >> 8, c = g & 255;
    float acc = p.b2[c];
    for (int j = 0; j < NN; ++j) acc += An[i*ANLD + j] * d_HW2[j*HID + c];
    d_H2pre[g] = acc;
  }
  gbar(4, target);

  //---------------- Phase F: BN2+gvec+z+d1 (redundant per block), vec distributed ----------------
  if (t < HID) {
    float s = 0.0f;
    for (int i = 0; i < NN; ++i) s += d_H2pre[i*HID + t];
    float mean = s / 96.0f;
    float vs = 0.0f;
    for (int i = 0; i < NN; ++i) { float a = d_H2pre[i*HID + t] - mean; vs += a*a; }
    sm[t] = mean;
    si[t] = 1.0f / sqrtf(vs/96.0f + 1e-5f);
  }
  __syncthreads();
  if (t < HID) {
    float mean = sm[t], istd = si[t], ga = p.g2[t], be = p.be2[t];
    float s = 0.0f;
    for (int i = 0; i < NN; ++i)
      s += fmaxf((d_H2pre[i*HID + t] - mean)*istd*ga + be, 0.0f);
    sg[t] = s / 96.0f;
  }
  __syncthreads();
  if (t < ZD) {
    float am = p.bmu[t], al = p.blv[t];
    for (int c = 0; c < HID; ++c) {
      float gv = sg[c];
      am += gv * p.Wmu[c*ZD + t];
      al += gv * p.Wlv[c*ZD + t];
    }
    al = fminf(fmaxf(al, -4.0f), 4.0f);
    sz[t] = am + p.eps[t] * expf(0.5f * al);
  }
  __syncthreads();
  if (t < HID) {
    float acc = p.bd1[t];
    for (int d = 0; d < ZD; ++d) acc += sz[d] * p.Wd1[d*HID + t];
    sd1[t] = fmaxf(acc, 0.0f);
  }
  __syncthreads();
  if (g < NL) {                          // vec distributed over blocks 0..12
    float acc = p.bd2[g];
    for (int c = 0; c < HID; ++c) acc += sd1[c] * p.Wd2[c*NL + g];
    d_vec[g] = tanhf(acc);
  }
  gbar(5, target);

  //---------------- MPM prologue (block b == row i) ----------------
  const int kk = t >> 2;
  const int qq = t & 3;
  float breg[24];

  if (t < 64) {
    float s = p.adj[b*NN + t] + ((t < 32) ? p.adj[b*NN + 64 + t] : 0.0f);
    s = wsum(s);
    if (t == 0) sdegA = s + 1.0f;
    int j = t;
    bool is1 = (j != b) && (p.adj[b*NN + j] > 0.5f);
    unsigned long long m1 = __ballot(is1);
    if (is1) nbrL[__popcll(m1 & ((1ull << t) - 1))] = j;
    int c1 = __popcll(m1);
    bool is2 = (t < 32) && ((64 + t) != b) && (p.adj[b*NN + 64 + t] > 0.5f);
    unsigned long long m2 = __ballot(is2);
    if (is2) nbrL[c1 + __popcll(m2 & ((1ull << t) - 1))] = 64 + t;
    if (t == 0) s_cnt = c1 + __popcll(m2);
  }

  {
    float bs = 0.0f;
    const int lb = qq*24;
    #pragma unroll
    for (int s = 0; s < 24; ++s) {
      int l = lb + s;
      float v = 0.0f;
      if (l != kk) {
        int a  = kk < l ? kk : l;
        int cc = kk < l ? l : kk;
        v = 1.0f / (1.0f + expf(-d_vec[tri_idx(a, cc)]));
      }
      breg[s] = v;
      bs += v;
    }
    float tot = bs + __shfl_xor(bs, 1, 64);
    tot += __shfl_xor(tot, 2, 64);
    __syncthreads();
    if (qq == 0) ndrow[kk] = 1.0f / (fabsf(sdegA - (tot + 1.0f)) + 1.0f);
  }
  __syncthreads();

  //---------------- MPM: 50 iterations, 1 custom barrier each ----------------
  int cur = 0;
  for (int it = 0; it < ITERS; ++it) {
    float s2 = d_ssq[it];
    int ex;
    (void)frexpf(sqrtf(s2), &ex);
    float scale = ldexpf(1.0f, -ex);     // exact power-of-2 rescale (homogeneous step)
    const float4* Xsrc = d_X[cur];
    for (int i4 = t; i4 < NN*NN/4; i4 += NTHR) {
      float4 v = Xsrc[i4];
      v.x *= scale; v.y *= scale; v.z *= scale; v.w *= scale;
      Xls4[i4] = v;
    }
    __syncthreads();

    float acc = 0.0f;
    const int cnt = s_cnt;
    for (int n = 0; n < cnt; ++n) {
      const int j = nbrL[n];
      const float4* xp = reinterpret_cast<const float4*>(&Xls[j*NN + qq*24]);
      float vm = 0.0f;
      #pragma unroll
      for (int s6 = 0; s6 < 6; ++s6) {
        float4 xv = xp[s6];
        vm = fmaxf(vm, breg[4*s6+0] * xv.x);
        vm = fmaxf(vm, breg[4*s6+1] * xv.y);
        vm = fmaxf(vm, breg[4*s6+2] * xv.z);
        vm = fmaxf(vm, breg[4*s6+3] * xv.w);
      }
      vm = fmaxf(vm, __shfl_xor(vm, 1, 64));
      vm = fmaxf(vm, __shfl_xor(vm, 2, 64));
      acc += vm;
    }
    if (qq == 0) {
      float xn = Xls[b*NN + kk] * ndrow[kk] + acc;
      ((float*)d_X[cur ^ 1])[b*NN + kk] = xn;
      rowsq[kk] = xn * xn;
    }
    __syncthreads();
    if (t < 64) {
      float v = rowsq[t] + ((t < 32) ? rowsq[64 + t] : 0.0f);
      v = wsum(v);
      if (t == 0) atomicAdd(&d_ssq[it+1], v);
    }
    gbar(6 + it, target);
    cur ^= 1;
  }

  //---------------- final true normalization ----------------
  if (g < NN*NN) {
    float inv = 1.0f / sqrtf(d_ssq[ITERS]);
    p.out[g] = ((const float*)d_X[cur])[g] * inv;
  }

  if (b == 0 && t == 0)
    __hip_atomic_fetch_add(&d_epoch, 1, __ATOMIC_RELAXED, __HIP_MEMORY_SCOPE_AGENT);
}

extern "C" void kernel_launch(void* const* d_in, const int* in_sizes, int n_in,
                              void* d_out, int out_size, void* d_ws, size_t ws_size,
                              hipStream_t stream) {
  Params prm;
  prm.x   = (const float*)d_in[0];
  prm.ei  = (const int*  )d_in[1];
  prm.adj = (const float*)d_in[2];
  prm.W1  = (const float*)d_in[3];
  prm.b1  = (const float*)d_in[4];
  prm.g1  = (const float*)d_in[5];
  prm.be1 = (const float*)d_in[6];
  prm.W2  = (const float*)d_in[7];
  prm.b2  = (const float*)d_in[8];
  prm.g2  = (const float*)d_in[9];
  prm.be2 = (const float*)d_in[10];
  prm.Wmu = (const float*)d_in[11];
  prm.bmu = (const float*)d_in[12];
  prm.Wlv = (const float*)d_in[13];
  prm.blv = (const float*)d_in[14];
  prm.Wd1 = (const float*)d_in[15];
  prm.bd1 = (const float*)d_in[16];
  prm.Wd2 = (const float*)d_in[17];
  prm.bd2 = (const float*)d_in[18];
  prm.eps = (const float*)d_in[19];
  prm.out = (float*)d_out;

  void* args[] = { &prm };
  hipLaunchCooperativeKernel(reinterpret_cast<void*>(&gvae_kernel),
                             dim3(NBLK), dim3(NTHR), args, 0, stream);
}

// Round 4
// 525.945 us; speedup vs baseline: 3.1452x; 1.5979x over previous
//
#include <hip/hip_runtime.h>
#include <math.h>

#define NN    96
#define EE    1024
#define HID   256
#define IND   64
#define ZD    64
#define NL    4656
#define NBLK  96
#define NTHR  384
#define ITERS 50
#define NBARS 57
#define SHF   (HID*49)     // 12544 floats: Wd2 chunk (largest user); also A-build (9312),
                           // vec staging (4656), X-row staging (<=9216)

struct Params {
  const float* x; const int* ei; const float* adj;
  const float* W1; const float* b1; const float* g1; const float* be1;
  const float* W2; const float* b2; const float* g2; const float* be2;
  const float* Wmu; const float* bmu; const float* Wlv; const float* blv;
  const float* Wd1; const float* bd1; const float* Wd2; const float* bd2;
  const float* eps; float* out;
};

// All cross-block data lives behind agent-scope (sc1 / MALL-coherent) accesses,
// so barriers need NO cache writeback/invalidate (the 12.5us/barrier cost in R2).
__device__ float d_XW[NN*HID];
__device__ float d_H1pre[NN*HID];
__device__ float d_HW2[NN*HID];
__device__ float d_H2pre[NN*HID];
__device__ float d_mean1[HID], d_istd1[HID];
__device__ float d_gvec[HID];
__device__ float d_vec[NL];
__device__ float d_Xg[2][NN*NN];
__device__ float d_ssq[ITERS+1];
// flag barrier: per-block monotonic epoch-flags (never reset; +NBARS per launch)
__device__ int   d_flag[NBLK];
__device__ int   d_epoch;

__device__ __forceinline__ float gld(const float* p) {
  return __hip_atomic_load(p, __ATOMIC_RELAXED, __HIP_MEMORY_SCOPE_AGENT);
}
__device__ __forceinline__ void gst(float* p, float v) {
  __hip_atomic_store(p, v, __ATOMIC_RELAXED, __HIP_MEMORY_SCOPE_AGENT);
}

__device__ __forceinline__ float wsum(float v) {
  v += __shfl_xor(v, 32, 64);
  v += __shfl_xor(v, 16, 64);
  v += __shfl_xor(v,  8, 64);
  v += __shfl_xor(v,  4, 64);
  v += __shfl_xor(v,  2, 64);
  v += __shfl_xor(v,  1, 64);
  return v;
}

__device__ __forceinline__ int tri_idx(int a, int c) {
  return a*95 - (a*(a-1))/2 + (c - a - 1);
}

// Fence-free grid barrier. Each wave drains its own sc1 stores (vmcnt covers
// ack at the coherence point), block-sync, t0 publishes its flag (sc1 store),
// 96 spinner threads poll their own per-block flag, block-sync. No wbl2/inv.
__device__ __forceinline__ void gbar(int idx, int base) {
  asm volatile("s_waitcnt vmcnt(0)" ::: "memory");
  __syncthreads();
  const int tgt = base + idx + 1;
  if (threadIdx.x == 0)
    __hip_atomic_store(&d_flag[blockIdx.x], tgt, __ATOMIC_RELAXED, __HIP_MEMORY_SCOPE_AGENT);
  if (threadIdx.x < NBLK) {
    while (__hip_atomic_load(&d_flag[threadIdx.x], __ATOMIC_RELAXED, __HIP_MEMORY_SCOPE_AGENT) < tgt)
      __builtin_amdgcn_s_sleep(2);
  }
  __syncthreads();
}

__global__ void __launch_bounds__(NTHR) gvae_kernel(Params p) {
  const int b = blockIdx.x;
  const int t = threadIdx.x;

  __shared__ __align__(16) float SH[SHF];   // 50.2 KB, serially reused
  __shared__ float pre1[HID];               // H1pre row b, then h1 row (in place)
  __shared__ float sg[HID], sd1[HID], sz[ZD];
  __shared__ float dinv[NN];
  __shared__ float eV[NN];   __shared__ int eL[NN];  __shared__ int s_ecnt;
  __shared__ float ndrow[NN], rowsq[NN];    __shared__ int nbrL[NN];
  __shared__ float sdegA;    __shared__ int s_cnt;

  const int base = __hip_atomic_load(&d_epoch, __ATOMIC_RELAXED, __HIP_MEMORY_SCOPE_AGENT) * NBARS;

  //======== P0: build A (dense, dedup) -> dinv, encoder nbr list; XW row b; inits ========
  for (int i = t; i < NN*97; i += NTHR) SH[i] = 0.0f;
  __syncthreads();
  for (int e = t; e < EE; e += NTHR) {
    int s = p.ei[e], d = p.ei[EE + e];
    SH[s*97 + d] = 1.0f;                    // benign same-value LDS races
  }
  if (t < NN) SH[t*97 + t] = 1.0f;          // max(A, I)
  __syncthreads();
  if (t < NN) {
    float s = 0.0f;
    for (int j = 0; j < NN; ++j) s += SH[t*97 + j];
    dinv[t] = 1.0f / sqrtf(s);
  }
  if (t < 64) {                              // encoder nbr list of row b (incl self), ascending
    bool is1 = SH[b*97 + t] > 0.5f;
    unsigned long long m1 = __ballot(is1);
    if (is1) eL[__popcll(m1 & ((1ull << t) - 1))] = t;
    int c1 = __popcll(m1);
    bool is2 = (t < 32) && SH[b*97 + 64 + t] > 0.5f;
    unsigned long long m2 = __ballot(is2);
    if (is2) eL[c1 + __popcll(m2 & ((1ull << t) - 1))] = 64 + t;
    if (t == 0) s_ecnt = c1 + __popcll(m2);
  }
  __syncthreads();
  if (t < s_ecnt) eV[t] = dinv[b] * dinv[eL[t]];
  if (t < HID) {                             // XW row b = x[b,:] @ W1 (inputs cached)
    float acc = 0.0f;
    for (int d = 0; d < IND; ++d) acc += p.x[b*IND + d] * p.W1[d*HID + t];
    gst(&d_XW[b*HID + t], acc);
  }
  if (t < NN) gst(&d_Xg[0][b*NN + t], 1.0f/96.0f);
  if (b == 0 && t <= ITERS) gst(&d_ssq[t], (t == 0) ? 1.0f : 0.0f);
  gbar(0, base);

  //======== P1: H1pre row b = sum_nbr An[b,j]*XW[j,:] + b1 (sparse, ~12 rows sc1) ========
  {
    const int lim = s_ecnt * HID;            // <= 96*256, typically ~3k
    float tv[16];
    #pragma unroll
    for (int r = 0; r < 16; ++r) {           // batched sc1 loads: one latency, not 16
      int idx = t + r*NTHR;
      if (idx < lim) tv[r] = gld(&d_XW[eL[idx >> 8]*HID + (idx & 255)]);
    }
    #pragma unroll
    for (int r = 0; r < 16; ++r) {
      int idx = t + r*NTHR;
      if (idx < lim) SH[idx] = tv[r];
    }
    for (int idx = t + 16*NTHR; idx < lim; idx += NTHR)   // rare high-degree fallback
      SH[idx] = gld(&d_XW[eL[idx >> 8]*HID + (idx & 255)]);
    __syncthreads();
    if (t < HID) {
      float acc = 0.0f;
      const int ec = s_ecnt;
      for (int n = 0; n < ec; ++n) acc += eV[n] * SH[n*HID + t];
      acc += p.b1[t];
      pre1[t] = acc;
      gst(&d_H1pre[b*HID + t], acc);
    }
  }
  gbar(1, base);

  //======== P2: BN1 stats — block b owns columns 3b..3b+2 (one warp each) ========
  if (b < 86) {
    int w = t >> 6, lane = t & 63;
    int c = b*3 + w;
    if (w < 3 && c < HID) {
      float v0 = gld(&d_H1pre[lane*HID + c]);
      float v1 = (lane < 32) ? gld(&d_H1pre[(64+lane)*HID + c]) : 0.0f;
      float mean = wsum(v0 + v1) * (1.0f/96.0f);
      float a0 = v0 - mean, a1 = (lane < 32) ? (v1 - mean) : 0.0f;
      float var = wsum(a0*a0 + a1*a1) * (1.0f/96.0f);
      if (lane == 0) { gst(&d_mean1[c], mean); gst(&d_istd1[c], 1.0f/sqrtf(var + 1e-5f)); }
    }
  }
  gbar(2, base);

  //======== P3: h1 row (local) -> HW2 row b = h1 @ W2 (W2 cached, coalesced) ========
  if (t < HID) {
    float m = gld(&d_mean1[t]), is = gld(&d_istd1[t]);
    pre1[t] = fmaxf((pre1[t] - m) * is * p.g1[t] + p.be1[t], 0.0f);
  }
  __syncthreads();
  if (t < HID) {
    float acc = 0.0f;
    for (int k = 0; k < HID; ++k) acc += pre1[k] * p.W2[k*HID + t];
    gst(&d_HW2[b*HID + t], acc);
  }
  gbar(3, base);

  //======== P4: H2pre row b = sum_nbr An[b,j]*HW2[j,:] + b2 ========
  {
    const int lim = s_ecnt * HID;
    float tv[16];
    #pragma unroll
    for (int r = 0; r < 16; ++r) {
      int idx = t + r*NTHR;
      if (idx < lim) tv[r] = gld(&d_HW2[eL[idx >> 8]*HID + (idx & 255)]);
    }
    #pragma unroll
    for (int r = 0; r < 16; ++r) {
      int idx = t + r*NTHR;
      if (idx < lim) SH[idx] = tv[r];
    }
    for (int idx = t + 16*NTHR; idx < lim; idx += NTHR)
      SH[idx] = gld(&d_HW2[eL[idx >> 8]*HID + (idx & 255)]);
    __syncthreads();
    if (t < HID) {
      float acc = 0.0f;
      const int ec = s_ecnt;
      for (int n = 0; n < ec; ++n) acc += eV[n] * SH[n*HID + t];
      acc += p.b2[t];
      gst(&d_H2pre[b*HID + t], acc);
    }
  }
  gbar(4, base);

  //======== P5: BN2 stats + gvec column — block b owns columns 3b..3b+2 ========
  if (b < 86) {
    int w = t >> 6, lane = t & 63;
    int c = b*3 + w;
    if (w < 3 && c < HID) {
      float v0 = gld(&d_H2pre[lane*HID + c]);
      float v1 = (lane < 32) ? gld(&d_H2pre[(64+lane)*HID + c]) : 0.0f;
      float mean = wsum(v0 + v1) * (1.0f/96.0f);
      float a0 = v0 - mean, a1 = (lane < 32) ? (v1 - mean) : 0.0f;
      float var = wsum(a0*a0 + a1*a1) * (1.0f/96.0f);
      float is = 1.0f / sqrtf(var + 1e-5f);
      float ga = p.g2[c], be = p.be2[c];
      float h0 = fmaxf((v0 - mean)*is*ga + be, 0.0f);
      float h1v = (lane < 32) ? fmaxf((v1 - mean)*is*ga + be, 0.0f) : 0.0f;
      float gs = wsum(h0 + h1v);
      if (lane == 0) gst(&d_gvec[c], gs * (1.0f/96.0f));
    }
  }
  gbar(5, base);

  //======== P6: z, d1 (block-local), vec chunk (49 outputs/block, Wd2 via LDS) ========
  if (t < HID) sg[t] = gld(&d_gvec[t]);
  __syncthreads();
  if (t < ZD) {
    float am = p.bmu[t], al = p.blv[t];
    for (int c = 0; c < HID; ++c) {
      float gv = sg[c];
      am += gv * p.Wmu[c*ZD + t];
      al += gv * p.Wlv[c*ZD + t];
    }
    al = fminf(fmaxf(al, -4.0f), 4.0f);
    sz[t] = am + p.eps[t] * expf(0.5f * al);
  }
  __syncthreads();
  if (t < HID) {
    float acc = p.bd1[t];
    for (int d = 0; d < ZD; ++d) acc += sz[d] * p.Wd1[d*HID + t];
    sd1[t] = fmaxf(acc, 0.0f);
  }
  __syncthreads();
  {
    const int o0 = b*49;
    const int nout = min(49, NL - o0);       // 49 per block; block 95 gets 1
    // stage Wd2[:, o0:o0+48] into SH (HID*49 = 12544 floats, fits SHF exactly).
    // Compile-time divisor 49; guard global read past column NL (block 95 only).
    #pragma unroll 4
    for (int idx = t; idx < HID*49; idx += NTHR) {
      int k = idx / 49, o = idx - k*49;
      SH[idx] = (o0 + o < NL) ? p.Wd2[k*NL + o0 + o] : 0.0f;
    }
    __syncthreads();
    if (t < nout) {
      float acc = p.bd2[o0 + t];
      for (int k = 0; k < HID; ++k) acc += sd1[k] * SH[k*49 + t];
      gst(&d_vec[o0 + t], tanhf(acc));
    }
  }
  gbar(6, base);

  //======== MPM prologue: stage vec -> LDS; adj nbr list; B row in regs; ndrow ========
  {
    float tv[13];
    #pragma unroll
    for (int r = 0; r < 13; ++r) {
      int idx = t + r*NTHR;
      if (idx < NL) tv[r] = gld(&d_vec[idx]);
    }
    #pragma unroll
    for (int r = 0; r < 13; ++r) {
      int idx = t + r*NTHR;
      if (idx < NL) SH[idx] = tv[r];
    }
  }
  const int kk = t >> 2;
  const int qq = t & 3;
  if (t < 64) {
    float s = p.adj[b*NN + t] + ((t < 32) ? p.adj[b*NN + 64 + t] : 0.0f);
    s = wsum(s);
    if (t == 0) sdegA = s + 1.0f;
    bool is1 = (t != b) && (p.adj[b*NN + t] > 0.5f);
    unsigned long long m1 = __ballot(is1);
    if (is1) nbrL[__popcll(m1 & ((1ull << t) - 1))] = t;
    int c1 = __popcll(m1);
    bool is2 = (t < 32) && ((64 + t) != b) && (p.adj[b*NN + 64 + t] > 0.5f);
    unsigned long long m2 = __ballot(is2);
    if (is2) nbrL[c1 + __popcll(m2 & ((1ull << t) - 1))] = 64 + t;
    if (t == 0) s_cnt = c1 + __popcll(m2);
  }
  __syncthreads();

  float breg[24];
  {
    float bs = 0.0f;
    const int lb = qq*24;
    #pragma unroll
    for (int s = 0; s < 24; ++s) {
      int l = lb + s;
      float v = 0.0f;
      if (l != kk) {
        int a  = kk < l ? kk : l;
        int cc = kk < l ? l : kk;
        v = 1.0f / (1.0f + expf(-SH[tri_idx(a, cc)]));
      }
      breg[s] = v;
      bs += v;
    }
    float tot = bs + __shfl_xor(bs, 1, 64);
    tot += __shfl_xor(tot, 2, 64);
    if (qq == 0) ndrow[kk] = 1.0f / (fabsf(sdegA - (tot + 1.0f)) + 1.0f);
  }
  __syncthreads();     // all breg reads of SH done; SH free for X staging

  //======== MPM: 50 iterations, 1 fence-free barrier each; stage only deg+1 X rows ========
  int cur = 0;
  for (int it = 0; it < ITERS; ++it) {
    float s2 = gld(&d_ssq[it]);
    int ex;
    (void)frexpf(sqrtf(s2), &ex);
    float scale = ldexpf(1.0f, -ex);          // exact pow2 rescale (homogeneous step;
                                              // cancels EXACTLY in final normalize)
    const int cnt = s_cnt;
    const int lim = (cnt + 1) * NN;           // nbr rows + own row (slot cnt)
    const float* Xs = d_Xg[cur];
    {
      float tv[8];
      #pragma unroll
      for (int r = 0; r < 8; ++r) {           // batched sc1 row gather
        int idx = t + r*NTHR;
        if (idx < lim) {
          int slot = idx / NN, col = idx - slot*NN;
          int j = (slot == cnt) ? b : nbrL[slot];
          tv[r] = gld(&Xs[j*NN + col]);
        }
      }
      #pragma unroll
      for (int r = 0; r < 8; ++r) {
        int idx = t + r*NTHR;
        if (idx < lim) SH[idx] = tv[r] * scale;
      }
      for (int idx = t + 8*NTHR; idx < lim; idx += NTHR) {   // deg>31 fallback
        int slot = idx / NN, col = idx - slot*NN;
        int j = (slot == cnt) ? b : nbrL[slot];
        SH[idx] = gld(&Xs[j*NN + col]) * scale;
      }
    }
    __syncthreads();

    float acc = 0.0f;
    for (int n = 0; n < cnt; ++n) {
      const float4* xp = reinterpret_cast<const float4*>(&SH[n*NN + qq*24]);
      float vm = 0.0f;
      #pragma unroll
      for (int s6 = 0; s6 < 6; ++s6) {
        float4 xv = xp[s6];
        vm = fmaxf(vm, breg[4*s6+0] * xv.x);
        vm = fmaxf(vm, breg[4*s6+1] * xv.y);
        vm = fmaxf(vm, breg[4*s6+2] * xv.z);
        vm = fmaxf(vm, breg[4*s6+3] * xv.w);
      }
      vm = fmaxf(vm, __shfl_xor(vm, 1, 64));
      vm = fmaxf(vm, __shfl_xor(vm, 2, 64));
      acc += vm;                               // ascending-j order = reference order
    }
    if (qq == 0) {
      float xn = SH[cnt*NN + kk] * ndrow[kk] + acc;
      gst(&d_Xg[cur ^ 1][b*NN + kk], xn);
      rowsq[kk] = xn * xn;
    }
    __syncthreads();
    if (t < 64) {
      float v = rowsq[t] + ((t < 32) ? rowsq[64 + t] : 0.0f);
      v = wsum(v);
      if (t == 0)
        __hip_atomic_fetch_add(&d_ssq[it+1], v, __ATOMIC_RELAXED, __HIP_MEMORY_SCOPE_AGENT);
    }
    gbar(7 + it, base);
    cur ^= 1;
  }

  //======== final true normalization ========
  if (t < NN) {
    float inv = 1.0f / sqrtf(gld(&d_ssq[ITERS]));
    p.out[b*NN + t] = gld(&d_Xg[cur][b*NN + t]) * inv;
  }
  if (b == 0 && t == 0)
    __hip_atomic_fetch_add(&d_epoch, 1, __ATOMIC_RELAXED, __HIP_MEMORY_SCOPE_AGENT);
}

extern "C" void kernel_launch(void* const* d_in, const int* in_sizes, int n_in,
                              void* d_out, int out_size, void* d_ws, size_t ws_size,
                              hipStream_t stream) {
  Params prm;
  prm.x   = (const float*)d_in[0];
  prm.ei  = (const int*  )d_in[1];
  prm.adj = (const float*)d_in[2];
  prm.W1  = (const float*)d_in[3];
  prm.b1  = (const float*)d_in[4];
  prm.g1  = (const float*)d_in[5];
  prm.be1 = (const float*)d_in[6];
  prm.W2  = (const float*)d_in[7];
  prm.b2  = (const float*)d_in[8];
  prm.g2  = (const float*)d_in[9];
  prm.be2 = (const float*)d_in[10];
  prm.Wmu = (const float*)d_in[11];
  prm.bmu = (const float*)d_in[12];
  prm.Wlv = (const float*)d_in[13];
  prm.blv = (const float*)d_in[14];
  prm.Wd1 = (const float*)d_in[15];
  prm.bd1 = (const float*)d_in[16];
  prm.Wd2 = (const float*)d_in[17];
  prm.bd2 = (const float*)d_in[18];
  prm.eps = (const float*)d_in[19];
  prm.out = (float*)d_out;

  void* args[] = { &prm };
  hipLaunchCooperativeKernel(reinterpret_cast<void*>(&gvae_kernel),
                             dim3(NBLK), dim3(NTHR), args, 0, stream);
}